// Round 15
// baseline (863.455 us; speedup 1.0000x reference)
//
#include <hip/hip_runtime.h>
#include <hip/hip_bf16.h>
#include <math.h>

#define HD 2048
#define ID 1024
#define NE 32
#define TOPK 4
#define NTOK 4096
#define NSLOT (NTOK*TOPK)

typedef __attribute__((ext_vector_type(4))) float f32x4;
typedef __attribute__((ext_vector_type(8))) short bf16x8;
typedef unsigned short u16;
typedef unsigned int u32;

typedef const void __attribute__((address_space(1)))* gas_p;
typedef void __attribute__((address_space(3)))* las_p;

static __device__ __forceinline__ void gload16(const void* g, void* l) {
  __builtin_amdgcn_global_load_lds((gas_p)g, (las_p)l, 16, 0, 0);
}

static __device__ __forceinline__ u16 f2bf(float f) {
  union { float f; u32 u; } v; v.f = f;
  u32 r = v.u + 0x7fffu + ((v.u >> 16) & 1u);
  return (u16)(r >> 16);
}

// ---------------- transpose + fp32->bf16 convert (R4-verified) ----------------
// src [R][C] fp32 -> dst [C][R] bf16 ; grid (C/64, R/64, nmat)
__global__ __launch_bounds__(256) void k_tcvt(const float* __restrict__ src,
                                              u16* __restrict__ dst,
                                              int R, int C) {
  __shared__ float tile[64][68];
  int t = threadIdx.x;
  size_t matoff = (size_t)blockIdx.z * R * C;
  const float* s = src + matoff;
  u16* d = dst + matoff;
  int c0 = blockIdx.x * 64, r0 = blockIdx.y * 64;
  int tx = t & 15, rr = t >> 4;
  #pragma unroll
  for (int i = 0; i < 4; ++i) {
    int r = rr + 16*i;
    float4 v = *(const float4*)(s + (size_t)(r0 + r)*C + c0 + tx*4);
    tile[r][tx*4+0] = v.x; tile[r][tx*4+1] = v.y;
    tile[r][tx*4+2] = v.z; tile[r][tx*4+3] = v.w;
  }
  __syncthreads();
  int orow = t >> 2, seg = t & 3;
  #pragma unroll
  for (int h = 0; h < 2; ++h) {
    float f[8];
    #pragma unroll
    for (int j = 0; j < 8; ++j) f[j] = tile[h*32 + seg*8 + j][orow];
    uint4 o;
    o.x = (u32)f2bf(f[0]) | ((u32)f2bf(f[1])<<16);
    o.y = (u32)f2bf(f[2]) | ((u32)f2bf(f[3])<<16);
    o.z = (u32)f2bf(f[4]) | ((u32)f2bf(f[5])<<16);
    o.w = (u32)f2bf(f[6]) | ((u32)f2bf(f[7])<<16);
    *(uint4*)(d + (size_t)(c0 + orow)*R + r0 + h*32 + seg*8) = o;
  }
}

// ---------------- fused RMSNorm + residual-prefill + gate ----------------
__global__ __launch_bounds__(256) void k_prep(const float* __restrict__ x,
                                              const float* __restrict__ w,
                                              const float* __restrict__ gw,
                                              u16* __restrict__ xn,
                                              float* __restrict__ out,
                                              int* __restrict__ topk_id,
                                              float* __restrict__ topk_w,
                                              int* __restrict__ counts) {
  __shared__ float xs[HD];
  __shared__ float red[4];
  __shared__ float logits[NE];
  int t = blockIdx.x, tid = threadIdx.x;
  const float* row = x + (size_t)t*HD;
  float4 v0 = ((const float4*)row)[tid*2+0];
  float4 v1 = ((const float4*)row)[tid*2+1];
  float* orow = out + (size_t)t * HD;
  ((float4*)orow)[tid*2+0] = v0;
  ((float4*)orow)[tid*2+1] = v1;
  float ss = v0.x*v0.x+v0.y*v0.y+v0.z*v0.z+v0.w*v0.w
           + v1.x*v1.x+v1.y*v1.y+v1.z*v1.z+v1.w*v1.w;
  #pragma unroll
  for (int d=1; d<64; d<<=1) ss += __shfl_xor(ss, d);
  if ((tid&63)==0) red[tid>>6] = ss;
  __syncthreads();
  float rs = rsqrtf((red[0]+red[1]+red[2]+red[3]) * (1.0f/HD) + 1e-6f);
  const float* wp = w + tid*8;
  float a[8] = {v0.x,v0.y,v0.z,v0.w,v1.x,v1.y,v1.z,v1.w};
  float nv[8];
  #pragma unroll
  for (int j=0;j<8;++j) { nv[j] = a[j]*rs*wp[j]; xs[tid*8+j] = nv[j]; }
  uint4 o;
  o.x = (u32)f2bf(nv[0]) | ((u32)f2bf(nv[1])<<16);
  o.y = (u32)f2bf(nv[2]) | ((u32)f2bf(nv[3])<<16);
  o.z = (u32)f2bf(nv[4]) | ((u32)f2bf(nv[5])<<16);
  o.w = (u32)f2bf(nv[6]) | ((u32)f2bf(nv[7])<<16);
  ((uint4*)xn)[(size_t)t*(HD/8) + tid] = o;
  __syncthreads();
  int wave = tid>>6, lane = tid&63;
  for (int ei=0; ei<8; ++ei) {
    int e = wave*8 + ei;
    const float* g = gw + (size_t)e*HD;
    float s = 0.f;
    #pragma unroll
    for (int j=0;j<HD/64;++j) s += xs[lane + j*64] * g[lane + j*64];
    #pragma unroll
    for (int d=1; d<64; d<<=1) s += __shfl_xor(s, d);
    if (lane==0) logits[e] = s;
  }
  __syncthreads();
  if (tid==0) {
    float best[TOPK]; int bid[TOPK]; unsigned used = 0;
    for (int k2=0;k2<TOPK;++k2) {
      float bv = -1e30f; int bi = 0;
      for (int i2=0;i2<NE;++i2)
        if (!((used>>i2)&1u) && logits[i2] > bv) { bv = logits[i2]; bi = i2; }
      used |= 1u<<bi; best[k2] = bv; bid[k2] = bi;
    }
    float mx = best[0], sum = 0.f, wv[TOPK];
    for (int k2=0;k2<TOPK;++k2) { wv[k2] = expf(best[k2]-mx); sum += wv[k2]; }
    float inv = 1.f/sum;
    for (int k2=0;k2<TOPK;++k2) {
      topk_id[t*TOPK+k2] = bid[k2];
      topk_w[t*TOPK+k2] = wv[k2]*inv;
      atomicAdd(&counts[bid[k2]], 1);
    }
  }
}

__global__ void k_zero(int* counts, int* cursors) {
  int i = threadIdx.x;
  if (i < NE) { counts[i] = 0; cursors[i] = 0; }
}

__global__ void k_scan(const int* __restrict__ counts, int* __restrict__ starts) {
  if (threadIdx.x==0 && blockIdx.x==0) {
    int acc = 0;
    for (int e=0;e<NE;++e) { starts[e] = acc; acc += counts[e]; }
  }
}

__global__ __launch_bounds__(256) void k_dispatch(const int* __restrict__ topk_id,
                                                  const float* __restrict__ topk_w,
                                                  const int* __restrict__ starts,
                                                  int* __restrict__ cursors,
                                                  int* __restrict__ slot_tok,
                                                  float* __restrict__ slot_w) {
  int i = blockIdx.x*256 + threadIdx.x;
  int e = topk_id[i];
  int p = atomicAdd(&cursors[e], 1);
  int slot = starts[e] + p;
  slot_tok[slot] = i >> 2;
  slot_w[slot] = topk_w[i];
}

// ============ Fused up-GEMM + SwiGLU (m97-style, bf16 B k-major) ============
// z<NE routed (w13t), z==NE shared (sgwt/suwt). Block 128 rows x 64 act cols
// (128 staged B cols, gate/up interleaved 16-col groups). Both operands via
// global_load_lds w16, XOR kseg involution (2-way free reads). R4-verified math.
__global__ __launch_bounds__(256) void k_gemm_up(
    const u16* __restrict__ A,
    const u16* __restrict__ w13t, const u16* __restrict__ sgwt,
    const u16* __restrict__ suwt,
    const int* __restrict__ counts, const int* __restrict__ starts,
    const int* __restrict__ slot_tok,
    u16* __restrict__ act, u16* __restrict__ sact) {
  __shared__ u16 Al[4096];
  __shared__ u16 Bl[4096];
  __shared__ int rowL[128];
  int t = threadIdx.x;
  int n0 = blockIdx.x * 64;
  int m0 = blockIdx.y * 128;
  int e  = blockIdx.z;
  bool routed = (e < NE);
  int M, rowbase;
  u16* actOut;
  if (routed) { M = counts[e]; rowbase = starts[e]; actOut = act; if (m0 >= M) return; }
  else { M = NTOK; rowbase = 0; actOut = sact; }
  if (t < 128) {
    int m = m0 + t;
    rowL[t] = routed ? slot_tok[rowbase + (m < M ? m : M-1)] : m;
  }
  __syncthreads();
  int r0i = t>>2, r1i = r0i + 64;
  int segA = ((t&3) ^ ((r0i>>1)&3)) << 3;
  const u16* srcA0 = A + (size_t)rowL[r0i]*HD + segA;
  const u16* srcA1 = A + (size_t)rowL[r1i]*HD + segA;
  // B: slots t (col c0=t>>2) and t+256 (col c1=c0+64); k-major rows in w13t/sgwt/suwt
  const u16* Bge = routed ? (w13t + (size_t)e*2*ID*HD) : sgwt;
  const u16* Bue = routed ? (w13t + (size_t)e*2*ID*HD + (size_t)ID*HD) : suwt;
  int c0 = t>>2, c1 = c0 + 64;
  int og0 = ((c0>>5)<<4)|(c0&15), og1 = ((c1>>5)<<4)|(c1&15);
  const u16* b0base = ((c0>>4)&1) ? Bue : Bge;
  const u16* b1base = ((c1>>4)&1) ? Bue : Bge;
  const u16* srcB0 = b0base + (size_t)(n0+og0)*HD + segA;
  const u16* srcB1 = b1base + (size_t)(n0+og1)*HD + segA;

  int lane = t&63, wave = t>>6, wr = wave>>1, wc = wave&1;
  int l15 = lane&15, l4 = lane>>4;
  int aoff[4], boff[4];
  #pragma unroll
  for (int f=0; f<4; ++f) {
    int r = wr*64 + f*16 + l15;
    aoff[f] = r*32 + ((l4 ^ ((r>>1)&3))<<3);
    int c = wc*64 + f*16 + l15;
    boff[f] = c*32 + ((l4 ^ ((c>>1)&3))<<3);
  }
  f32x4 acc[4][4];
  #pragma unroll
  for (int fm=0;fm<4;++fm)
    #pragma unroll
    for (int fn=0;fn<4;++fn)
      acc[fm][fn] = (f32x4){0.f,0.f,0.f,0.f};

  const int kiter = HD/32;
  for (int kt = 0; kt < kiter; ++kt) {
    gload16(srcA0, &Al[(size_t)t*8]);
    gload16(srcA1, &Al[2048 + (size_t)t*8]);
    gload16(srcB0, &Bl[(size_t)t*8]);
    gload16(srcB1, &Bl[2048 + (size_t)t*8]);
    srcA0 += 32; srcA1 += 32; srcB0 += 32; srcB1 += 32;
    __syncthreads();
    bf16x8 af[4], bfr[4];
    #pragma unroll
    for (int f=0; f<4; ++f) af[f] = *(const bf16x8*)&Al[aoff[f]];
    #pragma unroll
    for (int f=0; f<4; ++f) bfr[f] = *(const bf16x8*)&Bl[boff[f]];
    #pragma unroll
    for (int fm=0; fm<4; ++fm)
      #pragma unroll
      for (int fn=0; fn<4; ++fn)
        acc[fm][fn] = __builtin_amdgcn_mfma_f32_16x16x32_bf16(af[fm], bfr[fn], acc[fm][fn], 0,0,0);
    __syncthreads();
  }
  // epilogue: SwiGLU on (gate,up) fragment pairs
  #pragma unroll
  for (int fm=0; fm<4; ++fm) {
    #pragma unroll
    for (int fq=0; fq<2; ++fq) {
      f32x4 g = acc[fm][2*fq], u = acc[fm][2*fq+1];
      int col = n0 + (wc*2+fq)*16 + l15;
      #pragma unroll
      for (int r=0;r<4;++r) {
        int mloc = wr*64 + fm*16 + l4*4 + r;
        int m = m0 + mloc;
        if (m < M) {
          float gv = g[r];
          float av = gv / (1.f + expf(-gv)) * u[r];
          actOut[(size_t)(rowbase+m)*ID + col] = f2bf(av);
        }
      }
    }
  }
}

// ============ Fused down-GEMM (m97-style, bf16 B k-major): atomicAdd onto out ============
__global__ __launch_bounds__(256) void k_gemm_down(
    const u16* __restrict__ act, const u16* __restrict__ sact,
    const u16* __restrict__ w2t, const u16* __restrict__ sdwt,
    const int* __restrict__ counts, const int* __restrict__ starts,
    const int* __restrict__ slot_tok, const float* __restrict__ slot_w,
    float* __restrict__ out) {
  __shared__ u16 Al[4096];
  __shared__ u16 Bl[4096];
  __shared__ int tokL[128];
  __shared__ float wL[128];
  int t = threadIdx.x;
  int n0 = blockIdx.x * 128;
  int m0 = blockIdx.y * 128;
  int e  = blockIdx.z;
  bool routed = (e < NE);
  int M, rowbase;
  const u16* A;
  if (routed) { M = counts[e]; rowbase = starts[e]; A = act; if (m0 >= M) return; }
  else { M = NTOK; rowbase = 0; A = sact; }
  if (routed && t < 128) {
    int m = m0 + t;
    tokL[t] = (m<M) ? slot_tok[rowbase+m] : 0;
    wL[t]   = (m<M) ? slot_w[rowbase+m]  : 0.f;
  }
  if (routed) __syncthreads();
  int r0i = t>>2, r1i = r0i + 64;
  int segA = ((t&3) ^ ((r0i>>1)&3)) << 3;
  int am0 = m0 + r0i, am1 = m0 + r1i;
  const u16* srcA0 = A + (size_t)(rowbase + (am0 < M ? am0 : M-1))*ID + segA;
  const u16* srcA1 = A + (size_t)(rowbase + (am1 < M ? am1 : M-1))*ID + segA;
  const u16* Be = routed ? (w2t + (size_t)e*HD*ID) : sdwt;
  const u16* srcB0 = Be + (size_t)(n0 + r0i)*ID + segA;
  const u16* srcB1 = Be + (size_t)(n0 + r1i)*ID + segA;

  int lane = t&63, wave = t>>6, wr = wave>>1, wc = wave&1;
  int l15 = lane&15, l4 = lane>>4;
  int aoff[4], boff[4];
  #pragma unroll
  for (int f=0; f<4; ++f) {
    int r = wr*64 + f*16 + l15;
    aoff[f] = r*32 + ((l4 ^ ((r>>1)&3))<<3);
    int c = wc*64 + f*16 + l15;
    boff[f] = c*32 + ((l4 ^ ((c>>1)&3))<<3);
  }
  f32x4 acc[4][4];
  #pragma unroll
  for (int fm=0;fm<4;++fm)
    #pragma unroll
    for (int fn=0;fn<4;++fn)
      acc[fm][fn] = (f32x4){0.f,0.f,0.f,0.f};

  const int kiter = ID/32;
  for (int kt = 0; kt < kiter; ++kt) {
    gload16(srcA0, &Al[(size_t)t*8]);
    gload16(srcA1, &Al[2048 + (size_t)t*8]);
    gload16(srcB0, &Bl[(size_t)t*8]);
    gload16(srcB1, &Bl[2048 + (size_t)t*8]);
    srcA0 += 32; srcA1 += 32; srcB0 += 32; srcB1 += 32;
    __syncthreads();
    bf16x8 af[4], bfr[4];
    #pragma unroll
    for (int f=0; f<4; ++f) af[f] = *(const bf16x8*)&Al[aoff[f]];
    #pragma unroll
    for (int f=0; f<4; ++f) bfr[f] = *(const bf16x8*)&Bl[boff[f]];
    #pragma unroll
    for (int fm=0; fm<4; ++fm)
      #pragma unroll
      for (int fn=0; fn<4; ++fn)
        acc[fm][fn] = __builtin_amdgcn_mfma_f32_16x16x32_bf16(af[fm], bfr[fn], acc[fm][fn], 0,0,0);
    __syncthreads();
  }
  #pragma unroll
  for (int fm=0; fm<4; ++fm) {
    #pragma unroll
    for (int fn=0; fn<4; ++fn) {
      f32x4 v = acc[fm][fn];
      int col = n0 + wc*64 + fn*16 + l15;
      #pragma unroll
      for (int r=0;r<4;++r) {
        int mloc = wr*64 + fm*16 + l4*4 + r;
        int m = m0 + mloc;
        if (m < M) {
          if (routed) {
            atomicAdd(&out[(size_t)tokL[mloc]*HD + col], v[r]*wL[mloc]);
          } else {
            atomicAdd(&out[(size_t)m*HD + col], v[r]);
          }
        }
      }
    }
  }
}

extern "C" void kernel_launch(void* const* d_in, const int* in_sizes, int n_in,
                              void* d_out, int out_size, void* d_ws, size_t ws_size,
                              hipStream_t stream) {
  const float* x    = (const float*)d_in[0];
  const float* nw   = (const float*)d_in[1];
  const float* gw   = (const float*)d_in[2];
  const float* w13  = (const float*)d_in[3];
  const float* w2   = (const float*)d_in[4];
  const float* sgw  = (const float*)d_in[5];
  const float* suw  = (const float*)d_in[6];
  const float* sdw  = (const float*)d_in[7];
  float* out = (float*)d_out;

  char* p = (char*)d_ws;
  u16* w13t = (u16*)p;  p += (size_t)NE*2*ID*HD*2;   // [E][2I][H] bf16 (gate 0..I-1, up I..2I-1)
  u16* w2t  = (u16*)p;  p += (size_t)NE*HD*ID*2;     // [E][H][I] bf16
  u16* sgwt = (u16*)p;  p += (size_t)ID*HD*2;        // [I][H]
  u16* suwt = (u16*)p;  p += (size_t)ID*HD*2;        // [I][H]
  u16* sdwt = (u16*)p;  p += (size_t)HD*ID*2;        // [H][I]
  u16* xn   = (u16*)p;  p += (size_t)NTOK*HD*2;
  u16* act  = (u16*)p;  p += (size_t)NSLOT*ID*2;
  u16* sact = (u16*)p;  p += (size_t)NTOK*ID*2;
  int*   topk_id  = (int*)p;   p += (size_t)NTOK*TOPK*4;
  float* topk_w   = (float*)p; p += (size_t)NTOK*TOPK*4;
  int*   slot_tok = (int*)p;   p += (size_t)NSLOT*4;
  float* slot_w   = (float*)p; p += (size_t)NSLOT*4;
  int*   counts   = (int*)p;   p += 64*4;
  int*   cursors  = (int*)p;   p += 64*4;
  int*   starts   = (int*)p;   p += 64*4;

  k_zero<<<1, 64, 0, stream>>>(counts, cursors);
  k_prep<<<NTOK, 256, 0, stream>>>(x, nw, gw, xn, out, topk_id, topk_w, counts);
  k_scan<<<1, 1, 0, stream>>>(counts, starts);
  k_dispatch<<<NSLOT/256, 256, 0, stream>>>(topk_id, topk_w, starts, cursors, slot_tok, slot_w);

  // one-time weight transpose+convert to bf16 k-major
  k_tcvt<<<dim3(2*ID/64, HD/64, NE), 256, 0, stream>>>(w13, w13t, HD, 2*ID);
  k_tcvt<<<dim3(HD/64, ID/64, NE), 256, 0, stream>>>(w2, w2t, ID, HD);
  k_tcvt<<<dim3(ID/64, HD/64, 1), 256, 0, stream>>>(sgw, sgwt, HD, ID);
  k_tcvt<<<dim3(ID/64, HD/64, 1), 256, 0, stream>>>(suw, suwt, HD, ID);
  k_tcvt<<<dim3(HD/64, ID/64, 1), 256, 0, stream>>>(sdw, sdwt, ID, HD);

  // fused up-proj + swiglu: z<NE routed experts, z==NE shared experts
  k_gemm_up<<<dim3(ID/64, 32, NE+1), 256, 0, stream>>>(
      xn, w13t, sgwt, suwt, counts, starts, slot_tok, act, sact);
  // fused down-proj: atomicAdd onto residual-prefilled out
  k_gemm_down<<<dim3(HD/128, 32, NE+1), 256, 0, stream>>>(
      act, sact, w2t, sdwt, counts, starts, slot_tok, slot_w, out);
}